// Round 3
// baseline (420.755 us; speedup 1.0000x reference)
//
#include <hip/hip_runtime.h>
#include <math.h>

#define N_NODES 10000
#define N_GRAPHS 64
#define E_RAW 320000
#define E_ALL (E_RAW + N_NODES)   // 330000 edges incl. self-loops
#define NEG_SLOPE 0.2f
#define EPS 1e-16f

typedef unsigned short ushort_t;
typedef short short8 __attribute__((ext_vector_type(8)));
typedef float floatx4 __attribute__((ext_vector_type(4)));

static __device__ __forceinline__ float bfl(unsigned u) {
  union { unsigned u; float f; } v; v.u = u << 16; return v.f;
}
static __device__ __forceinline__ float bfh(unsigned u) {
  union { unsigned u; float f; } v; v.u = u & 0xFFFF0000u; return v.f;
}
static __device__ __forceinline__ ushort_t f2bf(float f) {  // RNE
  union { float f; unsigned u; } v; v.f = f;
  unsigned r = v.u + 0x7FFFu + ((v.u >> 16) & 1u);
  return (ushort_t)(r >> 16);
}

// ---------------- f32 -> bf16 convert (n % 4 == 0) ----------------
__global__ void cvt_bf16_k(const float* __restrict__ in, ushort_t* __restrict__ out, int n) {
  int i = (blockIdx.x * blockDim.x + threadIdx.x) * 4;
  if (i >= n) return;
  float4 v = *(const float4*)(in + i);
  ushort4 o;
  o.x = f2bf(v.x); o.y = f2bf(v.y); o.z = f2bf(v.z); o.w = f2bf(v.w);
  *(ushort4*)(out + i) = o;
}

// ---------------- W [K,N] f32 -> bf16 swizzled into MFMA B-operand order ----------------
// tile (kt,nt): 32 k x 16 n. lane l holds B[kt*32+(l>>4)*8+j][nt*16+(l&15)], j=0..7.
// Wsw[((kt*NT+nt)*64 + l)*8 + j]
__global__ void swizzle_w_k(const float* __restrict__ W, ushort_t* __restrict__ Wsw,
                            int K, int N) {
  int idx = blockIdx.x * blockDim.x + threadIdx.x;
  int NT = N >> 4;
  int total = (K >> 5) * NT * 64;
  if (idx >= total) return;
  int lane = idx & 63, tile = idx >> 6;
  int nt = tile % NT, kt = tile / NT;
  int n = nt * 16 + (lane & 15);
  int kb = kt * 32 + (lane >> 4) * 8;
  ushort4 lo, hi;
  lo.x = f2bf(W[(size_t)(kb + 0) * N + n]); lo.y = f2bf(W[(size_t)(kb + 1) * N + n]);
  lo.z = f2bf(W[(size_t)(kb + 2) * N + n]); lo.w = f2bf(W[(size_t)(kb + 3) * N + n]);
  hi.x = f2bf(W[(size_t)(kb + 4) * N + n]); hi.y = f2bf(W[(size_t)(kb + 5) * N + n]);
  hi.z = f2bf(W[(size_t)(kb + 6) * N + n]); hi.w = f2bf(W[(size_t)(kb + 7) * N + n]);
  *(ushort4*)(Wsw + (size_t)idx * 8) = lo;
  *(ushort4*)(Wsw + (size_t)idx * 8 + 4) = hi;
}

// ---------------- bf16 MFMA GEMM, no LDS, fused bf16-store + attention logits ----------------
// C[M,N] = A[M,K] @ B[K,N]; block = 4 waves (2x2), wave computes 64x64 (4x4 frags of 16x16x32).
// grid = (N/128, ceil(M/128)). K % 32 == 0, N % 128 == 0.
// Epilogue: Cb (bf16) store + asO/adO[r,h] += sum_c D[r,c]*a{S,D}[h,c&127]  (f32 atomics)
__global__ __launch_bounds__(256) void gemm_mfma_k(const ushort_t* __restrict__ A,
                                                   const ushort_t* __restrict__ Bsw,
                                                   ushort_t* __restrict__ Cb,
                                                   const float* __restrict__ aS,
                                                   const float* __restrict__ aD,
                                                   float* __restrict__ asO,
                                                   float* __restrict__ adO,
                                                   int M, int N, int K) {
  const int t = threadIdx.x, lane = t & 63, w = t >> 6;
  const int wm = w >> 1, wn = w & 1;
  const int m0 = blockIdx.y * 128 + wm * 64;
  const int n0 = blockIdx.x * 128 + wn * 64;
  const int g = lane >> 4, l16 = lane & 15;
  const int NT = N >> 4, H = N >> 7;

  floatx4 acc[4][4] = {};
  for (int k0 = 0; k0 < K; k0 += 32) {
    short8 a[4], b[4];
    #pragma unroll
    for (int i = 0; i < 4; i++) {
      int r = m0 + i * 16 + l16;
      r = r < M ? r : M - 1;                       // clamp; result discarded
      a[i] = *(const short8*)(A + (size_t)r * K + k0 + g * 8);
      int ntile = (n0 >> 4) + i;
      b[i] = *(const short8*)(Bsw + ((size_t)((k0 >> 5) * NT + ntile) * 64 + lane) * 8);
    }
    #pragma unroll
    for (int mi = 0; mi < 4; mi++)
      #pragma unroll
      for (int ni = 0; ni < 4; ni++)
        acc[mi][ni] = __builtin_amdgcn_mfma_f32_16x16x32_bf16(a[mi], b[ni], acc[mi][ni], 0, 0, 0);
  }

  #pragma unroll
  for (int mi = 0; mi < 4; mi++) {
    #pragma unroll
    for (int ni = 0; ni < 4; ni++) {
      int rb = m0 + mi * 16 + g * 4;               // rows rb..rb+3 (reg 0..3)
      int c  = n0 + ni * 16 + l16;
      int h  = (n0 + ni * 16) >> 7;                // 16-col tile never crosses a head
      float sp[4], dp[4];
      #pragma unroll
      for (int reg = 0; reg < 4; reg++) {
        float v = acc[mi][ni][reg];
        if (rb + reg < M) Cb[(size_t)(rb + reg) * N + c] = f2bf(v);
        float as = aS[h * 128 + (c & 127)];
        float ad = aD[h * 128 + (c & 127)];
        sp[reg] = v * as;
        dp[reg] = v * ad;
      }
      #pragma unroll
      for (int off = 8; off; off >>= 1) {
        #pragma unroll
        for (int reg = 0; reg < 4; reg++) {
          sp[reg] += __shfl_down(sp[reg], off, 16);
          dp[reg] += __shfl_down(dp[reg], off, 16);
        }
      }
      if (l16 == 0) {
        #pragma unroll
        for (int reg = 0; reg < 4; reg++) {
          int r = rb + reg;
          if (r < M) {
            atomicAdd(&asO[r * H + h], sp[reg]);
            atomicAdd(&adO[r * H + h], dp[reg]);
          }
        }
      }
    }
  }
}

// ---------------- CSR build ----------------
__global__ void degree_k(const int* __restrict__ ei, int* __restrict__ deg) {
  int e = blockIdx.x * blockDim.x + threadIdx.x;
  if (e >= E_ALL) return;
  int d = (e < E_RAW) ? ei[E_RAW + e] : (e - E_RAW);
  atomicAdd(&deg[d], 1);
}

__global__ __launch_bounds__(1024) void scan_k(const int* __restrict__ deg,
                                               int* __restrict__ rowptr,
                                               int* __restrict__ wof) {
  __shared__ int part[1024];
  int t = threadIdx.x;
  int base = t * 10;
  int local[10];
  int s = 0;
  #pragma unroll
  for (int i = 0; i < 10; i++) {
    int idx = base + i;
    local[i] = s;
    s += (idx < N_NODES) ? deg[idx] : 0;
  }
  part[t] = s;
  __syncthreads();
  for (int off = 1; off < 1024; off <<= 1) {
    int v = (t >= off) ? part[t - off] : 0;
    __syncthreads();
    part[t] += v;
    __syncthreads();
  }
  int pre = t ? part[t - 1] : 0;
  #pragma unroll
  for (int i = 0; i < 10; i++) {
    int idx = base + i;
    if (idx < N_NODES) {
      int val = pre + local[i];
      rowptr[idx] = val;
      wof[idx] = val;
    }
  }
  if (t == 1023) rowptr[N_NODES] = part[1023];
}

__global__ void fill_k(const int* __restrict__ ei, int* __restrict__ wof,
                       int* __restrict__ csr) {
  int e = blockIdx.x * blockDim.x + threadIdx.x;
  if (e >= E_ALL) return;
  int s, d;
  if (e < E_RAW) { s = ei[e]; d = ei[E_RAW + e]; }
  else           { s = d = e - E_RAW; }
  int pos = atomicAdd(&wof[d], 1);
  csr[pos] = s;
}

// ---------------- layer-1 softmax + aggregation + bias + ELU (bf16 out) ----------------
__global__ __launch_bounds__(128) void agg1_k(const ushort_t* __restrict__ xlb,
                                              const float* __restrict__ as1,
                                              const float* __restrict__ ad1,
                                              const float* __restrict__ b1,
                                              const int* __restrict__ rowptr,
                                              const int* __restrict__ csr,
                                              ushort_t* __restrict__ out) {
  int dst = blockIdx.x, t = threadIdx.x;
  int beg = rowptr[dst], deg = rowptr[dst + 1] - beg;
  int h2 = t & 7, slot = t >> 3;   // stats mapping: 16 slots x 8 heads
  int h = t >> 4;                  // aggregation head of channels 8t..8t+7
  float adh2 = ad1[dst * 8 + h2];
  __shared__ float sred[8][17];
  __shared__ float mh[8], sh[8];
  // pass 1: per-head max
  float pm = -1e30f;
  for (int e = slot; e < deg; e += 16) {
    float v = as1[csr[beg + e] * 8 + h2] + adh2;
    v = v > 0.f ? v : NEG_SLOPE * v;
    pm = fmaxf(pm, v);
  }
  sred[h2][slot] = pm;
  __syncthreads();
  if (t < 8) {
    float m = sred[t][0];
    for (int i = 1; i < 16; i++) m = fmaxf(m, sred[t][i]);
    mh[t] = m;
  }
  __syncthreads();
  float m2 = mh[h2];
  // pass 2: per-head sum of exp
  float ps = 0.f;
  for (int e = slot; e < deg; e += 16) {
    float v = as1[csr[beg + e] * 8 + h2] + adh2;
    v = v > 0.f ? v : NEG_SLOPE * v;
    ps += __expf(v - m2);
  }
  __syncthreads();
  sred[h2][slot] = ps;
  __syncthreads();
  if (t < 8) {
    float s = 0.f;
    for (int i = 0; i < 16; i++) s += sred[t][i];
    sh[t] = 1.0f / (s + EPS);
  }
  __syncthreads();
  float inv2 = sh[h2];
  // pass 3: weighted aggregation
  __shared__ float al[16][9];
  __shared__ int ss[16];
  float acc[8] = {};
  for (int base = 0; base < deg; base += 16) {
    int nn = min(16, deg - base);
    __syncthreads();
    if (slot < nn) {
      int s = csr[beg + base + slot];
      if (h2 == 0) ss[slot] = s;
      float v = as1[s * 8 + h2] + adh2;
      v = v > 0.f ? v : NEG_SLOPE * v;
      al[slot][h2] = __expf(v - m2) * inv2;
    }
    __syncthreads();
    #pragma unroll 4
    for (int e = 0; e < nn; e++) {
      float a = al[e][h];
      const uint4 u = *(const uint4*)(xlb + (size_t)ss[e] * 1024 + 8 * t);
      acc[0] = fmaf(a, bfl(u.x), acc[0]); acc[1] = fmaf(a, bfh(u.x), acc[1]);
      acc[2] = fmaf(a, bfl(u.y), acc[2]); acc[3] = fmaf(a, bfh(u.y), acc[3]);
      acc[4] = fmaf(a, bfl(u.z), acc[4]); acc[5] = fmaf(a, bfh(u.z), acc[5]);
      acc[6] = fmaf(a, bfl(u.w), acc[6]); acc[7] = fmaf(a, bfh(u.w), acc[7]);
    }
  }
  ushort_t hv[8];
  #pragma unroll
  for (int j = 0; j < 8; j++) {
    int o = 8 * t + j;
    float v = acc[j] + b1[o];
    v = v > 0.f ? v : (expf(v) - 1.0f);  // ELU
    hv[j] = f2bf(v);
  }
  uint4 up;
  up.x = (unsigned)hv[0] | ((unsigned)hv[1] << 16);
  up.y = (unsigned)hv[2] | ((unsigned)hv[3] << 16);
  up.z = (unsigned)hv[4] | ((unsigned)hv[5] << 16);
  up.w = (unsigned)hv[6] | ((unsigned)hv[7] << 16);
  *(uint4*)(out + (size_t)dst * 1024 + 8 * t) = up;
}

// ---------------- layer-2 softmax + aggregation + bias + ELU + pooling ----------------
__global__ __launch_bounds__(64) void agg2_k(const ushort_t* __restrict__ xlb2,
                                             const float* __restrict__ as2,
                                             const float* __restrict__ ad2,
                                             const float* __restrict__ b2,
                                             const int* __restrict__ rowptr,
                                             const int* __restrict__ csr,
                                             const int* __restrict__ batch,
                                             float* __restrict__ poolsum) {
  int dst = blockIdx.x, t = threadIdx.x;
  int beg = rowptr[dst], deg = rowptr[dst + 1] - beg;
  float adv = ad2[dst];
  float pm = -1e30f;
  for (int e = t; e < deg; e += 64) {
    float v = as2[csr[beg + e]] + adv;
    v = v > 0.f ? v : NEG_SLOPE * v;
    pm = fmaxf(pm, v);
  }
  #pragma unroll
  for (int off = 32; off; off >>= 1) pm = fmaxf(pm, __shfl_xor(pm, off));
  float m = pm;
  float ps = 0.f;
  for (int e = t; e < deg; e += 64) {
    float v = as2[csr[beg + e]] + adv;
    v = v > 0.f ? v : NEG_SLOPE * v;
    ps += __expf(v - m);
  }
  #pragma unroll
  for (int off = 32; off; off >>= 1) ps += __shfl_xor(ps, off);
  float inv = 1.0f / (ps + EPS);
  __shared__ float al[64];
  __shared__ int ss[64];
  float acc0 = 0.f, acc1 = 0.f;
  for (int base = 0; base < deg; base += 64) {
    int nn = min(64, deg - base);
    __syncthreads();
    if (t < nn) {
      int s = csr[beg + base + t];
      ss[t] = s;
      float v = as2[s] + adv;
      v = v > 0.f ? v : NEG_SLOPE * v;
      al[t] = __expf(v - m) * inv;
    }
    __syncthreads();
    #pragma unroll 4
    for (int e = 0; e < nn; e++) {
      unsigned u = *(const unsigned*)(xlb2 + (size_t)ss[e] * 128 + 2 * t);
      acc0 = fmaf(al[e], bfl(u), acc0);
      acc1 = fmaf(al[e], bfh(u), acc1);
    }
  }
  int c0 = 2 * t;
  float v0 = acc0 + b2[c0];
  float v1 = acc1 + b2[c0 + 1];
  v0 = v0 > 0.f ? v0 : (expf(v0) - 1.0f);
  v1 = v1 > 0.f ? v1 : (expf(v1) - 1.0f);
  int g = batch[dst];
  atomicAdd(&poolsum[g * 128 + c0], v0);
  atomicAdd(&poolsum[g * 128 + c0 + 1], v1);
}

__global__ void count_k(const int* __restrict__ batch, int* __restrict__ cnt) {
  int n = blockIdx.x * blockDim.x + threadIdx.x;
  if (n < N_NODES) atomicAdd(&cnt[batch[n]], 1);
}

// ---------------- pooled MLP head ----------------
__global__ __launch_bounds__(128) void final_k(const float* __restrict__ poolsum,
                                               const int* __restrict__ cnt,
                                               const float* __restrict__ l1w,
                                               const float* __restrict__ l1b,
                                               const float* __restrict__ l2w,
                                               const float* __restrict__ l2b,
                                               float* __restrict__ out) {
  int g = blockIdx.x, t = threadIdx.x;
  __shared__ float pooled[128];
  float c = fmaxf((float)cnt[g], 1.0f);
  pooled[t] = poolsum[g * 128 + t] / c;
  __syncthreads();
  float acc = l1b[t];
  for (int i = 0; i < 128; i++) acc = fmaf(pooled[i], l1w[i * 128 + t], acc);
  acc = fmaxf(acc, 0.0f);  // ReLU
  float p = acc * l2w[t];
  #pragma unroll
  for (int off = 32; off; off >>= 1) p += __shfl_down(p, off);
  __shared__ float r[2];
  if ((t & 63) == 0) r[t >> 6] = p;
  __syncthreads();
  if (t == 0) out[g] = r[0] + r[1] + l2b[0];
}

extern "C" void kernel_launch(void* const* d_in, const int* in_sizes, int n_in,
                              void* d_out, int out_size, void* d_ws, size_t ws_size,
                              hipStream_t stream) {
  const float* x    = (const float*)d_in[0];
  const int*   ei   = (const int*)d_in[1];
  const int*   batch= (const int*)d_in[2];
  const float* W1   = (const float*)d_in[3];
  const float* aS1  = (const float*)d_in[4];
  const float* aD1  = (const float*)d_in[5];
  const float* b1   = (const float*)d_in[6];
  const float* W2   = (const float*)d_in[7];
  const float* aS2  = (const float*)d_in[8];
  const float* aD2  = (const float*)d_in[9];
  const float* b2   = (const float*)d_in[10];
  const float* l1w  = (const float*)d_in[11];
  const float* l1b  = (const float*)d_in[12];
  const float* l2w  = (const float*)d_in[13];
  const float* l2b  = (const float*)d_in[14];
  float* out = (float*)d_out;

  // workspace layout (~48 MB)
  ushort_t* xlb1   = (ushort_t*)d_ws;                 // 10,240,000 bf16
  ushort_t* h1b    = xlb1 + 10240000;                 // 10,240,000 bf16
  ushort_t* xlb2   = h1b + 10240000;                  // 1,280,000 bf16
  ushort_t* xb     = xlb2 + 1280000;                  // 1,280,000 bf16
  ushort_t* W1sw   = xb + 1280000;                    // 131,072 bf16
  ushort_t* W2sw   = W1sw + 131072;                   // 131,072 bf16
  float*    zero0  = (float*)(W2sw + 131072);         // ---- zero block start ----
  float*    as1    = zero0;                           // 80,000 f
  float*    ad1    = as1 + 80000;                     // 80,000 f
  float*    as2    = ad1 + 80000;                     // 10,000 f
  float*    ad2    = as2 + 10000;                     // 10,000 f
  float*    poolsum= ad2 + 10000;                     // 8,192 f
  int*      poolcnt= (int*)(poolsum + 8192);          // 64 i
  int*      deg    = poolcnt + 64;                    // 10,000 i ---- zero block end ----
  int*      rowptr = deg + 10000;                     // 10,001 i
  int*      wof    = rowptr + 10001;                  // 10,000 i
  int*      csr    = wof + 10000;                     // 330,000 i

  size_t zero_elems = 80000 + 80000 + 10000 + 10000 + 8192 + 64 + 10000;
  hipMemsetAsync(zero0, 0, zero_elems * 4, stream);

  // input conversions
  cvt_bf16_k<<<(1280000 / 4 + 255) / 256, 256, 0, stream>>>(x, xb, 1280000);
  swizzle_w_k<<<(16384 + 255) / 256, 256, 0, stream>>>(W1, W1sw, 128, 1024);
  swizzle_w_k<<<(16384 + 255) / 256, 256, 0, stream>>>(W2, W2sw, 1024, 128);

  // CSR build
  int eb = (E_ALL + 255) / 256;
  degree_k<<<eb, 256, 0, stream>>>(ei, deg);
  scan_k<<<1, 1024, 0, stream>>>(deg, rowptr, wof);
  fill_k<<<eb, 256, 0, stream>>>(ei, wof, csr);

  // layer 1: MFMA GEMM (+ fused logits), then softmax-aggregate (bf16 out)
  gemm_mfma_k<<<dim3(8, 79), 256, 0, stream>>>(xb, W1sw, xlb1, aS1, aD1, as1, ad1,
                                               N_NODES, 1024, 128);
  agg1_k<<<N_NODES, 128, 0, stream>>>(xlb1, as1, ad1, b1, rowptr, csr, h1b);

  // layer 2
  gemm_mfma_k<<<dim3(1, 79), 256, 0, stream>>>(h1b, W2sw, xlb2, aS2, aD2, as2, ad2,
                                               N_NODES, 128, 1024);
  agg2_k<<<N_NODES, 64, 0, stream>>>(xlb2, as2, ad2, b2, rowptr, csr, batch, poolsum);

  // head
  count_k<<<(N_NODES + 255) / 256, 256, 0, stream>>>(batch, poolcnt);
  final_k<<<N_GRAPHS, 128, 0, stream>>>(poolsum, poolcnt, l1w, l1b, l2w, l2b, out);
}

// Round 4
// 329.921 us; speedup vs baseline: 1.2753x; 1.2753x over previous
//
#include <hip/hip_runtime.h>
#include <math.h>

#define N_NODES 10000
#define N_GRAPHS 64
#define E_RAW 320000
#define E_ALL (E_RAW + N_NODES)   // 330000 edges incl. self-loops
#define NEG_SLOPE 0.2f
#define EPS 1e-16f

typedef unsigned short ushort_t;
typedef short short8 __attribute__((ext_vector_type(8)));
typedef float floatx4 __attribute__((ext_vector_type(4)));

static __device__ __forceinline__ float bfl(unsigned u) {
  union { unsigned u; float f; } v; v.u = u << 16; return v.f;
}
static __device__ __forceinline__ float bfh(unsigned u) {
  union { unsigned u; float f; } v; v.u = u & 0xFFFF0000u; return v.f;
}
static __device__ __forceinline__ ushort_t f2bf(float f) {  // RNE
  union { float f; unsigned u; } v; v.f = f;
  unsigned r = v.u + 0x7FFFu + ((v.u >> 16) & 1u);
  return (ushort_t)(r >> 16);
}

// async global->LDS, 16 B per lane. ldsbase must be wave-uniform; lane i lands at
// ldsbase + 16*i. gp is per-lane.
static __device__ __forceinline__ void load16_lds(const ushort_t* gp, ushort_t* ldsbase, int lane) {
#if __has_builtin(__builtin_amdgcn_global_load_lds)
  __builtin_amdgcn_global_load_lds((const __attribute__((address_space(1))) void*)gp,
                                   (__attribute__((address_space(3))) void*)ldsbase, 16, 0, 0);
#else
  *(uint4*)(ldsbase + lane * 8) = *(const uint4*)gp;
#endif
}

// ---------------- f32 -> bf16 convert (n % 4 == 0) ----------------
__global__ void cvt_bf16_k(const float* __restrict__ in, ushort_t* __restrict__ out, int n) {
  int i = (blockIdx.x * blockDim.x + threadIdx.x) * 4;
  if (i >= n) return;
  float4 v = *(const float4*)(in + i);
  ushort4 o;
  o.x = f2bf(v.x); o.y = f2bf(v.y); o.z = f2bf(v.z); o.w = f2bf(v.w);
  *(ushort4*)(out + i) = o;
}

// ---------------- W [K,N] f32 -> bf16 swizzled into MFMA B-operand order ----------------
// tile (kt,nt): 32 k x 16 n. lane l holds B[kt*32+(l>>4)*8+j][nt*16+(l&15)], j=0..7.
// Wsw[((kt*NT+nt)*64 + l)*8 + j]
__global__ void swizzle_w_k(const float* __restrict__ W, ushort_t* __restrict__ Wsw,
                            int K, int N) {
  int idx = blockIdx.x * blockDim.x + threadIdx.x;
  int NT = N >> 4;
  int total = (K >> 5) * NT * 64;
  if (idx >= total) return;
  int lane = idx & 63, tile = idx >> 6;
  int nt = tile % NT, kt = tile / NT;
  int n = nt * 16 + (lane & 15);
  int kb = kt * 32 + (lane >> 4) * 8;
  ushort4 lo, hi;
  lo.x = f2bf(W[(size_t)(kb + 0) * N + n]); lo.y = f2bf(W[(size_t)(kb + 1) * N + n]);
  lo.z = f2bf(W[(size_t)(kb + 2) * N + n]); lo.w = f2bf(W[(size_t)(kb + 3) * N + n]);
  hi.x = f2bf(W[(size_t)(kb + 4) * N + n]); hi.y = f2bf(W[(size_t)(kb + 5) * N + n]);
  hi.z = f2bf(W[(size_t)(kb + 6) * N + n]); hi.w = f2bf(W[(size_t)(kb + 7) * N + n]);
  *(ushort4*)(Wsw + (size_t)idx * 8) = lo;
  *(ushort4*)(Wsw + (size_t)idx * 8 + 4) = hi;
}

// ---------------- GEMM layer 1: [10000,128] @ [128,1024] -> bf16 + fused logits ----------
// grid (8, 79), block 256 (4 waves 2x2), block tile 128x128, full K=128 staged once.
__global__ __launch_bounds__(256) void gemm1_k(const ushort_t* __restrict__ A,
                                               const ushort_t* __restrict__ Bsw,
                                               ushort_t* __restrict__ Cb,
                                               const float* __restrict__ aS,
                                               const float* __restrict__ aD,
                                               float* __restrict__ asO,
                                               float* __restrict__ adO) {
  const int M = N_NODES, K = 128, NT = 64;
  __shared__ ushort_t Albuf[32 * 512];     // 32 frag-tiles (mtl*4+kt), 32 KB
  __shared__ float epi[4][16][68];         // per-wave transpose buffer
  const int t = threadIdx.x, lane = t & 63, w = t >> 6;
  const int wm = w >> 1, wn = w & 1;
  const int m0 = blockIdx.y * 128;
  const int n0 = blockIdx.x * 128;
  const int g = lane >> 4, l16 = lane & 15;

  // stage A (frag order): wave w stages tiles w*8 .. w*8+7
  #pragma unroll
  for (int i = 0; i < 8; i++) {
    int tile = w * 8 + i;
    int mtl = tile >> 2, kt = tile & 3;
    int r = m0 + mtl * 16 + l16; r = r < M ? r : M - 1;
    load16_lds(A + (size_t)r * K + kt * 32 + g * 8, &Albuf[tile * 512], lane);
  }
  __syncthreads();

  floatx4 acc[4][4] = {};
  #pragma unroll
  for (int kt = 0; kt < 4; kt++) {
    short8 a[4], b[4];
    #pragma unroll
    for (int mi = 0; mi < 4; mi++)
      a[mi] = *(const short8*)&Albuf[(((wm * 4 + mi) * 4 + kt) * 64 + lane) * 8];
    #pragma unroll
    for (int ni = 0; ni < 4; ni++) {
      int nt = (n0 >> 4) + wn * 4 + ni;
      b[ni] = *(const short8*)(Bsw + ((size_t)(kt * NT + nt) * 64 + lane) * 8);
    }
    #pragma unroll
    for (int mi = 0; mi < 4; mi++)
      #pragma unroll
      for (int ni = 0; ni < 4; ni++)
        acc[mi][ni] = __builtin_amdgcn_mfma_f32_16x16x32_bf16(a[mi], b[ni], acc[mi][ni], 0, 0, 0);
  }

  // epilogue: LDS transpose -> coalesced bf16 stores + fused logits
  const int h = blockIdx.x;                // block spans exactly one head
  const int r = lane >> 2, c0 = (lane & 3) * 16;
  const int colh = wn * 64 + c0;           // col within head
  float asc[16], adc[16];
  #pragma unroll
  for (int c = 0; c < 16; c++) { asc[c] = aS[h * 128 + colh + c]; adc[c] = aD[h * 128 + colh + c]; }
  #pragma unroll
  for (int mi = 0; mi < 4; mi++) {
    #pragma unroll
    for (int ni = 0; ni < 4; ni++)
      #pragma unroll
      for (int reg = 0; reg < 4; reg++)
        epi[w][g * 4 + reg][ni * 16 + l16] = acc[mi][ni][reg];
    // same-wave DS ordering guarantees the reads below see the writes
    float4 v0 = *(float4*)&epi[w][r][c0];
    float4 v1 = *(float4*)&epi[w][r][c0 + 4];
    float4 v2 = *(float4*)&epi[w][r][c0 + 8];
    float4 v3 = *(float4*)&epi[w][r][c0 + 12];
    float vr[16] = {v0.x,v0.y,v0.z,v0.w, v1.x,v1.y,v1.z,v1.w,
                    v2.x,v2.y,v2.z,v2.w, v3.x,v3.y,v3.z,v3.w};
    int grow = m0 + wm * 64 + mi * 16 + r;
    float sp = 0.f, dp = 0.f;
    ushort_t hv[16];
    #pragma unroll
    for (int c = 0; c < 16; c++) {
      sp = fmaf(vr[c], asc[c], sp);
      dp = fmaf(vr[c], adc[c], dp);
      hv[c] = f2bf(vr[c]);
    }
    sp += __shfl_xor(sp, 1); sp += __shfl_xor(sp, 2);
    dp += __shfl_xor(dp, 1); dp += __shfl_xor(dp, 2);
    if (grow < M) {
      uint4 u0, u1;
      u0.x = (unsigned)hv[0] | ((unsigned)hv[1] << 16);
      u0.y = (unsigned)hv[2] | ((unsigned)hv[3] << 16);
      u0.z = (unsigned)hv[4] | ((unsigned)hv[5] << 16);
      u0.w = (unsigned)hv[6] | ((unsigned)hv[7] << 16);
      u1.x = (unsigned)hv[8] | ((unsigned)hv[9] << 16);
      u1.y = (unsigned)hv[10] | ((unsigned)hv[11] << 16);
      u1.z = (unsigned)hv[12] | ((unsigned)hv[13] << 16);
      u1.w = (unsigned)hv[14] | ((unsigned)hv[15] << 16);
      ushort_t* cp = Cb + (size_t)grow * 1024 + n0 + wn * 64 + c0;
      *(uint4*)cp = u0;
      *(uint4*)(cp + 8) = u1;
      if ((lane & 3) == 0) {
        atomicAdd(&asO[grow * 8 + h], sp);
        atomicAdd(&adO[grow * 8 + h], dp);
      }
    }
  }
}

// ---------------- GEMM layer 2: [10000,1024] @ [1024,128] -> bf16 + fused logits ----------
// grid (157), block 256 (4 waves 2x2), block tile 64x128, K chunked 8 x 128.
__global__ __launch_bounds__(256) void gemm2_k(const ushort_t* __restrict__ A,
                                               const ushort_t* __restrict__ Bsw,
                                               ushort_t* __restrict__ Cb,
                                               const float* __restrict__ aS,
                                               const float* __restrict__ aD,
                                               float* __restrict__ asO,
                                               float* __restrict__ adO) {
  const int M = N_NODES, K = 1024, NT = 8;
  __shared__ ushort_t Albuf[16 * 512];     // 16 frag-tiles per chunk, 16 KB
  __shared__ float epi[4][16][68];
  const int t = threadIdx.x, lane = t & 63, w = t >> 6;
  const int wm = w >> 1, wn = w & 1;
  const int mb0 = blockIdx.x * 64;
  const int g = lane >> 4, l16 = lane & 15;

  floatx4 acc[2][4] = {};
  for (int ch = 0; ch < 8; ch++) {
    #pragma unroll
    for (int i = 0; i < 4; i++) {
      int tile = w * 4 + i;
      int mtl = tile >> 2, kt = tile & 3;
      int r = mb0 + mtl * 16 + l16; r = r < M ? r : M - 1;
      load16_lds(A + (size_t)r * K + (ch * 4 + kt) * 32 + g * 8, &Albuf[tile * 512], lane);
    }
    __syncthreads();
    #pragma unroll
    for (int ks = 0; ks < 4; ks++) {
      short8 a[2], b[4];
      #pragma unroll
      for (int mi = 0; mi < 2; mi++)
        a[mi] = *(const short8*)&Albuf[(((wm * 2 + mi) * 4 + ks) * 64 + lane) * 8];
      #pragma unroll
      for (int ni = 0; ni < 4; ni++) {
        int nt = wn * 4 + ni, ktg = ch * 4 + ks;
        b[ni] = *(const short8*)(Bsw + ((size_t)(ktg * NT + nt) * 64 + lane) * 8);
      }
      #pragma unroll
      for (int mi = 0; mi < 2; mi++)
        #pragma unroll
        for (int ni = 0; ni < 4; ni++)
          acc[mi][ni] = __builtin_amdgcn_mfma_f32_16x16x32_bf16(a[mi], b[ni], acc[mi][ni], 0, 0, 0);
    }
    __syncthreads();
  }

  const int r = lane >> 2, c0 = (lane & 3) * 16;
  const int colh = wn * 64 + c0;           // col within the single 128-col head
  float asc[16], adc[16];
  #pragma unroll
  for (int c = 0; c < 16; c++) { asc[c] = aS[colh + c]; adc[c] = aD[colh + c]; }
  #pragma unroll
  for (int mi = 0; mi < 2; mi++) {
    #pragma unroll
    for (int ni = 0; ni < 4; ni++)
      #pragma unroll
      for (int reg = 0; reg < 4; reg++)
        epi[w][g * 4 + reg][ni * 16 + l16] = acc[mi][ni][reg];
    float4 v0 = *(float4*)&epi[w][r][c0];
    float4 v1 = *(float4*)&epi[w][r][c0 + 4];
    float4 v2 = *(float4*)&epi[w][r][c0 + 8];
    float4 v3 = *(float4*)&epi[w][r][c0 + 12];
    float vr[16] = {v0.x,v0.y,v0.z,v0.w, v1.x,v1.y,v1.z,v1.w,
                    v2.x,v2.y,v2.z,v2.w, v3.x,v3.y,v3.z,v3.w};
    int grow = mb0 + wm * 32 + mi * 16 + r;
    float sp = 0.f, dp = 0.f;
    ushort_t hv[16];
    #pragma unroll
    for (int c = 0; c < 16; c++) {
      sp = fmaf(vr[c], asc[c], sp);
      dp = fmaf(vr[c], adc[c], dp);
      hv[c] = f2bf(vr[c]);
    }
    sp += __shfl_xor(sp, 1); sp += __shfl_xor(sp, 2);
    dp += __shfl_xor(dp, 1); dp += __shfl_xor(dp, 2);
    if (grow < M) {
      uint4 u0, u1;
      u0.x = (unsigned)hv[0] | ((unsigned)hv[1] << 16);
      u0.y = (unsigned)hv[2] | ((unsigned)hv[3] << 16);
      u0.z = (unsigned)hv[4] | ((unsigned)hv[5] << 16);
      u0.w = (unsigned)hv[6] | ((unsigned)hv[7] << 16);
      u1.x = (unsigned)hv[8] | ((unsigned)hv[9] << 16);
      u1.y = (unsigned)hv[10] | ((unsigned)hv[11] << 16);
      u1.z = (unsigned)hv[12] | ((unsigned)hv[13] << 16);
      u1.w = (unsigned)hv[14] | ((unsigned)hv[15] << 16);
      ushort_t* cp = Cb + (size_t)grow * 128 + colh;
      *(uint4*)cp = u0;
      *(uint4*)(cp + 8) = u1;
      if ((lane & 3) == 0) {
        atomicAdd(&asO[grow], sp);
        atomicAdd(&adO[grow], dp);
      }
    }
  }
}

// ---------------- CSR build ----------------
__global__ void degree_k(const int* __restrict__ ei, int* __restrict__ deg) {
  int e = blockIdx.x * blockDim.x + threadIdx.x;
  if (e >= E_ALL) return;
  int d = (e < E_RAW) ? ei[E_RAW + e] : (e - E_RAW);
  atomicAdd(&deg[d], 1);
}

__global__ __launch_bounds__(1024) void scan_k(const int* __restrict__ deg,
                                               int* __restrict__ rowptr,
                                               int* __restrict__ wof) {
  __shared__ int part[1024];
  int t = threadIdx.x;
  int base = t * 10;
  int local[10];
  int s = 0;
  #pragma unroll
  for (int i = 0; i < 10; i++) {
    int idx = base + i;
    local[i] = s;
    s += (idx < N_NODES) ? deg[idx] : 0;
  }
  part[t] = s;
  __syncthreads();
  for (int off = 1; off < 1024; off <<= 1) {
    int v = (t >= off) ? part[t - off] : 0;
    __syncthreads();
    part[t] += v;
    __syncthreads();
  }
  int pre = t ? part[t - 1] : 0;
  #pragma unroll
  for (int i = 0; i < 10; i++) {
    int idx = base + i;
    if (idx < N_NODES) {
      int val = pre + local[i];
      rowptr[idx] = val;
      wof[idx] = val;
    }
  }
  if (t == 1023) rowptr[N_NODES] = part[1023];
}

__global__ void fill_k(const int* __restrict__ ei, int* __restrict__ wof,
                       int* __restrict__ csr) {
  int e = blockIdx.x * blockDim.x + threadIdx.x;
  if (e >= E_ALL) return;
  int s, d;
  if (e < E_RAW) { s = ei[e]; d = ei[E_RAW + e]; }
  else           { s = d = e - E_RAW; }
  int pos = atomicAdd(&wof[d], 1);
  csr[pos] = s;
}

// ---------------- layer-1 softmax + aggregation + bias + ELU (bf16 out) ----------------
__global__ __launch_bounds__(128) void agg1_k(const ushort_t* __restrict__ xlb,
                                              const float* __restrict__ as1,
                                              const float* __restrict__ ad1,
                                              const float* __restrict__ b1,
                                              const int* __restrict__ rowptr,
                                              const int* __restrict__ csr,
                                              ushort_t* __restrict__ out) {
  int dst = blockIdx.x, t = threadIdx.x;
  int beg = rowptr[dst], deg = rowptr[dst + 1] - beg;
  int h2 = t & 7, slot = t >> 3;   // stats mapping: 16 slots x 8 heads
  int h = t >> 4;                  // aggregation head of channels 8t..8t+7
  float adh2 = ad1[dst * 8 + h2];
  __shared__ float sred[8][17];
  __shared__ float mh[8], sh[8];
  float pm = -1e30f;
  for (int e = slot; e < deg; e += 16) {
    float v = as1[csr[beg + e] * 8 + h2] + adh2;
    v = v > 0.f ? v : NEG_SLOPE * v;
    pm = fmaxf(pm, v);
  }
  sred[h2][slot] = pm;
  __syncthreads();
  if (t < 8) {
    float m = sred[t][0];
    for (int i = 1; i < 16; i++) m = fmaxf(m, sred[t][i]);
    mh[t] = m;
  }
  __syncthreads();
  float m2 = mh[h2];
  float ps = 0.f;
  for (int e = slot; e < deg; e += 16) {
    float v = as1[csr[beg + e] * 8 + h2] + adh2;
    v = v > 0.f ? v : NEG_SLOPE * v;
    ps += __expf(v - m2);
  }
  __syncthreads();
  sred[h2][slot] = ps;
  __syncthreads();
  if (t < 8) {
    float s = 0.f;
    for (int i = 0; i < 16; i++) s += sred[t][i];
    sh[t] = 1.0f / (s + EPS);
  }
  __syncthreads();
  float inv2 = sh[h2];
  __shared__ float al[16][9];
  __shared__ int ss[16];
  float acc[8] = {};
  for (int base = 0; base < deg; base += 16) {
    int nn = min(16, deg - base);
    __syncthreads();
    if (slot < nn) {
      int s = csr[beg + base + slot];
      if (h2 == 0) ss[slot] = s;
      float v = as1[s * 8 + h2] + adh2;
      v = v > 0.f ? v : NEG_SLOPE * v;
      al[slot][h2] = __expf(v - m2) * inv2;
    }
    __syncthreads();
    #pragma unroll 4
    for (int e = 0; e < nn; e++) {
      float a = al[e][h];
      const uint4 u = *(const uint4*)(xlb + (size_t)ss[e] * 1024 + 8 * t);
      acc[0] = fmaf(a, bfl(u.x), acc[0]); acc[1] = fmaf(a, bfh(u.x), acc[1]);
      acc[2] = fmaf(a, bfl(u.y), acc[2]); acc[3] = fmaf(a, bfh(u.y), acc[3]);
      acc[4] = fmaf(a, bfl(u.z), acc[4]); acc[5] = fmaf(a, bfh(u.z), acc[5]);
      acc[6] = fmaf(a, bfl(u.w), acc[6]); acc[7] = fmaf(a, bfh(u.w), acc[7]);
    }
  }
  ushort_t hv[8];
  #pragma unroll
  for (int j = 0; j < 8; j++) {
    int o = 8 * t + j;
    float v = acc[j] + b1[o];
    v = v > 0.f ? v : (expf(v) - 1.0f);  // ELU
    hv[j] = f2bf(v);
  }
  uint4 up;
  up.x = (unsigned)hv[0] | ((unsigned)hv[1] << 16);
  up.y = (unsigned)hv[2] | ((unsigned)hv[3] << 16);
  up.z = (unsigned)hv[4] | ((unsigned)hv[5] << 16);
  up.w = (unsigned)hv[6] | ((unsigned)hv[7] << 16);
  *(uint4*)(out + (size_t)dst * 1024 + 8 * t) = up;
}

// ---------------- layer-2 softmax + aggregation + bias + ELU + pooling ----------------
__global__ __launch_bounds__(64) void agg2_k(const ushort_t* __restrict__ xlb2,
                                             const float* __restrict__ as2,
                                             const float* __restrict__ ad2,
                                             const float* __restrict__ b2,
                                             const int* __restrict__ rowptr,
                                             const int* __restrict__ csr,
                                             const int* __restrict__ batch,
                                             float* __restrict__ poolsum) {
  int dst = blockIdx.x, t = threadIdx.x;
  int beg = rowptr[dst], deg = rowptr[dst + 1] - beg;
  float adv = ad2[dst];
  float pm = -1e30f;
  for (int e = t; e < deg; e += 64) {
    float v = as2[csr[beg + e]] + adv;
    v = v > 0.f ? v : NEG_SLOPE * v;
    pm = fmaxf(pm, v);
  }
  #pragma unroll
  for (int off = 32; off; off >>= 1) pm = fmaxf(pm, __shfl_xor(pm, off));
  float m = pm;
  float ps = 0.f;
  for (int e = t; e < deg; e += 64) {
    float v = as2[csr[beg + e]] + adv;
    v = v > 0.f ? v : NEG_SLOPE * v;
    ps += __expf(v - m);
  }
  #pragma unroll
  for (int off = 32; off; off >>= 1) ps += __shfl_xor(ps, off);
  float inv = 1.0f / (ps + EPS);
  __shared__ float al[64];
  __shared__ int ss[64];
  float acc0 = 0.f, acc1 = 0.f;
  for (int base = 0; base < deg; base += 64) {
    int nn = min(64, deg - base);
    __syncthreads();
    if (t < nn) {
      int s = csr[beg + base + t];
      ss[t] = s;
      float v = as2[s] + adv;
      v = v > 0.f ? v : NEG_SLOPE * v;
      al[t] = __expf(v - m) * inv;
    }
    __syncthreads();
    #pragma unroll 4
    for (int e = 0; e < nn; e++) {
      unsigned u = *(const unsigned*)(xlb2 + (size_t)ss[e] * 128 + 2 * t);
      acc0 = fmaf(al[e], bfl(u), acc0);
      acc1 = fmaf(al[e], bfh(u), acc1);
    }
  }
  int c0 = 2 * t;
  float v0 = acc0 + b2[c0];
  float v1 = acc1 + b2[c0 + 1];
  v0 = v0 > 0.f ? v0 : (expf(v0) - 1.0f);
  v1 = v1 > 0.f ? v1 : (expf(v1) - 1.0f);
  int g = batch[dst];
  atomicAdd(&poolsum[g * 128 + c0], v0);
  atomicAdd(&poolsum[g * 128 + c0 + 1], v1);
}

__global__ void count_k(const int* __restrict__ batch, int* __restrict__ cnt) {
  int n = blockIdx.x * blockDim.x + threadIdx.x;
  if (n < N_NODES) atomicAdd(&cnt[batch[n]], 1);
}

// ---------------- pooled MLP head ----------------
__global__ __launch_bounds__(128) void final_k(const float* __restrict__ poolsum,
                                               const int* __restrict__ cnt,
                                               const float* __restrict__ l1w,
                                               const float* __restrict__ l1b,
                                               const float* __restrict__ l2w,
                                               const float* __restrict__ l2b,
                                               float* __restrict__ out) {
  int g = blockIdx.x, t = threadIdx.x;
  __shared__ float pooled[128];
  float c = fmaxf((float)cnt[g], 1.0f);
  pooled[t] = poolsum[g * 128 + t] / c;
  __syncthreads();
  float acc = l1b[t];
  for (int i = 0; i < 128; i++) acc = fmaf(pooled[i], l1w[i * 128 + t], acc);
  acc = fmaxf(acc, 0.0f);  // ReLU
  float p = acc * l2w[t];
  #pragma unroll
  for (int off = 32; off; off >>= 1) p += __shfl_down(p, off);
  __shared__ float r[2];
  if ((t & 63) == 0) r[t >> 6] = p;
  __syncthreads();
  if (t == 0) out[g] = r[0] + r[1] + l2b[0];
}

extern "C" void kernel_launch(void* const* d_in, const int* in_sizes, int n_in,
                              void* d_out, int out_size, void* d_ws, size_t ws_size,
                              hipStream_t stream) {
  const float* x    = (const float*)d_in[0];
  const int*   ei   = (const int*)d_in[1];
  const int*   batch= (const int*)d_in[2];
  const float* W1   = (const float*)d_in[3];
  const float* aS1  = (const float*)d_in[4];
  const float* aD1  = (const float*)d_in[5];
  const float* b1   = (const float*)d_in[6];
  const float* W2   = (const float*)d_in[7];
  const float* aS2  = (const float*)d_in[8];
  const float* aD2  = (const float*)d_in[9];
  const float* b2   = (const float*)d_in[10];
  const float* l1w  = (const float*)d_in[11];
  const float* l1b  = (const float*)d_in[12];
  const float* l2w  = (const float*)d_in[13];
  const float* l2b  = (const float*)d_in[14];
  float* out = (float*)d_out;

  // workspace layout (~48 MB)
  ushort_t* xlb1   = (ushort_t*)d_ws;                 // 10,240,000 bf16
  ushort_t* h1b    = xlb1 + 10240000;                 // 10,240,000 bf16
  ushort_t* xlb2   = h1b + 10240000;                  // 1,280,000 bf16
  ushort_t* xb     = xlb2 + 1280000;                  // 1,280,000 bf16
  ushort_t* W1sw   = xb + 1280000;                    // 131,072 bf16
  ushort_t* W2sw   = W1sw + 131072;                   // 131,072 bf16
  float*    zero0  = (float*)(W2sw + 131072);         // ---- zero block start ----
  float*    as1    = zero0;                           // 80,000 f
  float*    ad1    = as1 + 80000;                     // 80,000 f
  float*    as2    = ad1 + 80000;                     // 10,000 f
  float*    ad2    = as2 + 10000;                     // 10,000 f
  float*    poolsum= ad2 + 10000;                     // 8,192 f
  int*      poolcnt= (int*)(poolsum + 8192);          // 64 i
  int*      deg    = poolcnt + 64;                    // 10,000 i ---- zero block end ----
  int*      rowptr = deg + 10000;                     // 10,001 i
  int*      wof    = rowptr + 10001;                  // 10,000 i
  int*      csr    = wof + 10000;                     // 330,000 i

  size_t zero_elems = 80000 + 80000 + 10000 + 10000 + 8192 + 64 + 10000;
  hipMemsetAsync(zero0, 0, zero_elems * 4, stream);

  // input conversions
  cvt_bf16_k<<<(1280000 / 4 + 255) / 256, 256, 0, stream>>>(x, xb, 1280000);
  swizzle_w_k<<<(16384 + 255) / 256, 256, 0, stream>>>(W1, W1sw, 128, 1024);
  swizzle_w_k<<<(16384 + 255) / 256, 256, 0, stream>>>(W2, W2sw, 1024, 128);

  // CSR build
  int eb = (E_ALL + 255) / 256;
  degree_k<<<eb, 256, 0, stream>>>(ei, deg);
  scan_k<<<1, 1024, 0, stream>>>(deg, rowptr, wof);
  fill_k<<<eb, 256, 0, stream>>>(ei, wof, csr);

  // layer 1
  gemm1_k<<<dim3(8, 79), 256, 0, stream>>>(xb, W1sw, xlb1, aS1, aD1, as1, ad1);
  agg1_k<<<N_NODES, 128, 0, stream>>>(xlb1, as1, ad1, b1, rowptr, csr, h1b);

  // layer 2
  gemm2_k<<<157, 256, 0, stream>>>(h1b, W2sw, xlb2, aS2, aD2, as2, ad2);
  agg2_k<<<N_NODES, 64, 0, stream>>>(xlb2, as2, ad2, b2, rowptr, csr, batch, poolsum);

  // head
  count_k<<<(N_NODES + 255) / 256, 256, 0, stream>>>(batch, poolcnt);
  final_k<<<N_GRAPHS, 128, 0, stream>>>(poolsum, poolcnt, l1w, l1b, l2w, l2b, out);
}